// Round 7
// baseline (187.150 us; speedup 1.0000x reference)
//
#include <hip/hip_runtime.h>
#include <hip/hip_bf16.h>

#define U_CNT 339
#define S_CNT 5825
#define N_CNT 6164          // U + S
#define D_DIM 128
#define R_DIM 32
#define B_CNT 500000
#define NNZ_U 200000        // edges with u-row (first half of rows=concat(u,s))
#define H_DIM 64
#define LN_EPS 1e-5f

// ---- padded dims ----
#define SPAD 5856           // 183*32  (s padded to K-granularity 32)
#define UPAD 352            // 11*32   (u padded)
#define KT_S 183            // s as K: 5856/32
#define KT_U 11             // u as K: 352/32
#define NT_S 365            // s as N: 5840/16 (>= 5825)
#define NT_U 22             // u as N: 352/16
#define U_KCHUNK 23         // 8*23 = 184 >= 183 (8-way split-K)

#define ET_U16 (D_DIM * SPAD)          // s-side E^T plane (ushorts)
#define PKS_U16 (KT_U * NT_S * 512)    // B packed [k=u][n=s] MFMA B-frags
#define PKU_U16 (KT_S * NT_U * 512)    // B packed [k=s][n=u] MFMA B-frags
#define WT_U16  (H_DIM * UPAD)         // w^T [j][u] hi/lo planes
#define GU_U16  (UPAD * UPAD)          // Gu hi/lo planes, row-major
#define V_U16   (KT_U * 8 * 512)       // V = [y*Pc_u | Eu*Pc_i] as B-frags (352x128)

// k_pre units: 183 s-transpose + 11 u-transpose + 782 edge-pack + 9 Pc/weight
#define PRE_S_UNITS 183
#define PRE_U_UNITS 11
#define PRE_UT_END (PRE_S_UNITS + PRE_U_UNITS)            // 194
#define PRE_EDGE_UNITS ((NNZ_U + 255) / 256)              // 782
#define PRE_EDGE_END (PRE_UT_END + PRE_EDGE_UNITS)        // 976
#define PRE_UNITS (PRE_EDGE_END + 9)                      // 985

// k_heavy roles: 253 triangular GU tiles + 176 yT tiles, 512 thr
#define HV_GU_END 253                  // 22*23/2 (Gu symmetric: R6 post-mortem)
#define HV_YT_END 429
#define HV_BLOCKS 429

// fp32 weight-block offsets (elements)
#define WF_B1   4096
#define WF_G1   4160
#define WF_BE1  4224
#define WF_B2   4288
#define WF_G2   4352
#define WF_BE2  4416
#define WF_W3   4480
#define WF_B3   4544
#define WF_TOT  4545

#define MLP_BLOCKS 1280     // re-test post-DPP: R4's 1280-regression cause
                            // (LDS-pipe shuffles) was removed in R5

typedef __hip_bfloat16 bf16;
typedef __attribute__((ext_vector_type(8))) short sh8;   // 8 bf16 (MFMA A/B frag)
typedef __attribute__((ext_vector_type(4))) float f4v;   // MFMA C/D frag

__device__ __forceinline__ float b2f(bf16 x) { return __bfloat162float(x); }
__device__ __forceinline__ unsigned short f2bs(float f) {
    union { bf16 b; unsigned short s; } u;
    u.b = __float2bfloat16(f);
    return u.s;
}
__device__ __forceinline__ float bu2f(unsigned int lo16) {   // bf16 bits -> f32
    return __uint_as_float(lo16 << 16);
}
__device__ __forceinline__ float ldf(const void* p, long i, int isf32) {
    return isf32 ? ((const float*)p)[i] : b2f(((const bf16*)p)[i]);
}
// per-wave dtype detect (no flag buffer, no extra launch); wave-uniform result
__device__ __forceinline__ int detect_f32(const void* uE) {
    const unsigned short* p = (const unsigned short*)uE;
    int lane = threadIdx.x & 63;
    unsigned short v = p[2 * lane];
    int e = (v >> 7) & 0xFF;
    unsigned long long m = __ballot(e >= 127);
    return (m != 0ull) ? 1 : 0;
}

// ---- DPP within-16-lane sum reduction (pure VALU, no LDS pipe) ----
// R4->R5 verified: replacing 48 __shfl_xor with DPP cut MLP 58.6->44.8us.
template<int CTRL>
__device__ __forceinline__ float dpp_add(float x) {
    int t = __builtin_amdgcn_update_dpp(0, __float_as_int(x), CTRL, 0xF, 0xF, false);
    return x + __int_as_float(t);
}
__device__ __forceinline__ float rowsum16(float x) {
    x = dpp_add<0xB1>(x);    // quad_perm [1,0,3,2]  (xor 1)
    x = dpp_add<0x4E>(x);    // quad_perm [2,3,0,1]  (xor 2)
    x = dpp_add<0x124>(x);   // row_ror:4
    x = dpp_add<0x128>(x);   // row_ror:8
    return x;
}

// ---------- pre: s-transpose | u-transpose | edge pack | Pc/weight prep ----------
__global__ void __launch_bounds__(256)
k_pre(const void* __restrict__ iE,
      unsigned short* __restrict__ EtHi, unsigned short* __restrict__ EtLo,
      const int* __restrict__ rows, const int* __restrict__ cols,
      const void* __restrict__ vals,
      unsigned short* __restrict__ PkS, unsigned short* __restrict__ PkU,
      float* __restrict__ uEt,
      const void* __restrict__ uHy, const void* __restrict__ iHy,
      const void* __restrict__ W1, const void* __restrict__ W2,
      const void* __restrict__ b1, const void* __restrict__ g1,
      const void* __restrict__ be1, const void* __restrict__ b2,
      const void* __restrict__ g2, const void* __restrict__ be2,
      const void* __restrict__ W3, const void* __restrict__ b3,
      float* __restrict__ Pc, float* __restrict__ Wf,
      unsigned short* __restrict__ Wb,
      const void* __restrict__ uE) {
    __shared__ __align__(16) float sm[6688];          // 26.7 KB arena (max role)
    int tid = threadIdx.x;
    int isf32 = detect_f32(uE);
    int unit = blockIdx.x;
    if (unit < PRE_S_UNITS) {                         // s-node transpose role
        float* ls = sm;                               // [32][129]
        int sg0 = unit * 32;
        int nl = tid >> 3, dbase = (tid & 7) * 16;
        int s = sg0 + nl;
        #pragma unroll
        for (int i = 0; i < 16; ++i) {
            int d = dbase + i;
            float v = (s < S_CNT) ? ldf(iE, (long)s * D_DIM + d, isf32) : 0.f;
            ls[nl * 129 + d] = v;
        }
        __syncthreads();
        int nl2 = tid & 31;
        int s2 = sg0 + nl2;
        #pragma unroll
        for (int i = 0; i < 16; ++i) {
            int d = (tid >> 5) * 16 + i;
            float v = ls[nl2 * 129 + d];
            unsigned short hi = f2bs(v);
            unsigned short lo = f2bs(v - bu2f(hi));
            EtHi[(size_t)d * SPAD + s2] = hi;
            EtLo[(size_t)d * SPAD + s2] = lo;
        }
    } else if (unit < PRE_UT_END) {                   // u-node transpose (f32 out)
        float* ls = sm;
        int ug0 = (unit - PRE_S_UNITS) * 32;
        int nl = tid >> 3, dbase = (tid & 7) * 16;
        int u = ug0 + nl;
        #pragma unroll
        for (int i = 0; i < 16; ++i) {
            int d = dbase + i;
            float v = (u < U_CNT) ? ldf(uE, (long)u * D_DIM + d, isf32) : 0.f;
            ls[nl * 129 + d] = v;
        }
        __syncthreads();
        int nl2 = tid & 31;
        int u2 = ug0 + nl2;
        #pragma unroll
        for (int i = 0; i < 16; ++i) {
            int d = (tid >> 5) * 16 + i;
            uEt[(size_t)d * UPAD + u2] = ls[nl2 * 129 + d];
        }
    } else if (unit < PRE_EDGE_END) {                 // edge pack (u-rows only)
        int e = (unit - PRE_UT_END) * 256 + tid;
        if (e < NNZ_U) {
            int r = rows[e];
            if (r < U_CNT) {
                int u = r, s = cols[e] - U_CNT;
                unsigned short w = f2bs(ldf(vals, e, isf32));
                int kt = u >> 5, kq = (u >> 3) & 3, j = u & 7;
                int nt = s >> 4, nn = s & 15;
                PkS[((kt * NT_S + nt) * 64 + kq * 16 + nn) * 8 + j] = w;
                int kt2 = s >> 5, kq2 = (s >> 3) & 3, j2 = s & 7;
                int nt2 = u >> 4, nn2 = u & 15;
                PkU[((kt2 * NT_U + nt2) * 64 + kq2 * 16 + nn2) * 8 + j2] = w;
            }
        }
    } else {                                          // Pc / weight prep roles
        int rb = unit - PRE_EDGE_END;                 // 0..8
        if (rb == 8) {                                // weight prep
            for (int i = tid; i < 4096; i += 256) {
                int j = i & 7, lane = (i >> 3) & 63, kh = (i >> 9) & 1, t = i >> 10;
                int k = kh * 32 + ((lane >> 4) & 3) * 8 + j;
                int n = t * 16 + (lane & 15);
                Wb[i] = f2bs(ldf(W2, k * 64 + n, isf32));
            }
            for (int i = tid; i < WF_TOT - 4096; i += 256) {
                int g = 4096 + i;
                float v;
                if      (g < WF_G1)  v = ldf(b1,  g - WF_B1,   isf32);
                else if (g < WF_BE1) v = ldf(g1,  g - WF_G1,   isf32);
                else if (g < WF_B2)  v = ldf(be1, g - WF_BE1,  isf32);
                else if (g < WF_G2)  v = ldf(b2,  g - WF_B2,   isf32);
                else if (g < WF_BE2) v = ldf(g2,  g - WF_G2,   isf32);
                else if (g < WF_W3)  v = ldf(be2, g - WF_BE2,  isf32);
                else if (g < WF_B3)  v = ldf(W3,  g - WF_W3,   isf32);
                else                 v = ldf(b3,  0,           isf32);
                Wf[g] = v;
            }
            return;
        }
        int side = rb >> 2;                           // 0 = user, 1 = service
        int j0 = (rb & 3) * 16;                       // 16 Pc-columns per block
        const void* Hy = side ? iHy : uHy;            // [32][128]
        long wbase = (long)side * D_DIM * H_DIM;
        float* Hs = sm;                               // [32][129]
        float* Ws = sm + R_DIM * 129;                 // [128][16]
        float* Ts = Ws + D_DIM * 16;                  // [32][16]
        if (isf32) {
            const float* H = (const float*)Hy;
            for (int i = tid; i < R_DIM * D_DIM; i += 256)
                Hs[(i >> 7) * 129 + (i & 127)] = H[i];
            const float* Wp = (const float*)W1 + wbase;
            for (int i = tid; i < D_DIM * 16; i += 256)
                Ws[i] = Wp[(i >> 4) * H_DIM + j0 + (i & 15)];
        } else {
            const unsigned short* H = (const unsigned short*)Hy;
            for (int i = tid; i < R_DIM * D_DIM; i += 256)
                Hs[(i >> 7) * 129 + (i & 127)] = bu2f(H[i]);
            const unsigned short* Wp = (const unsigned short*)W1 + wbase;
            for (int i = tid; i < D_DIM * 16; i += 256)
                Ws[i] = bu2f(Wp[(i >> 4) * H_DIM + j0 + (i & 15)]);
        }
        __syncthreads();
        for (int idx = tid; idx < R_DIM * 16; idx += 256) {
            int a = idx >> 4, j = idx & 15;
            float acc = 0.f;
            #pragma unroll 8
            for (int d = 0; d < D_DIM; ++d)
                acc = fmaf(Hs[a * 129 + d], Ws[d * 16 + j], acc);
            Ts[idx] = acc;
        }
        __syncthreads();
        for (int idx = tid; idx < D_DIM * 16; idx += 256) {
            int d = idx >> 4, j = idx & 15;
            float acc = 0.f;
            #pragma unroll
            for (int a = 0; a < R_DIM; ++a)
                acc = fmaf(Hs[a * 129 + d], Ts[a * 16 + j], acc);
            Pc[side * D_DIM * H_DIM + d * H_DIM + j0 + j] = acc;
        }
    }
}

// ---------- heavy: 512 threads, 8-way split-K per tile ----------
// bid<253: triangular Gu tile (mt>=nt; symmetric -> mirror write; bitwise
// identical to computing the mirror tile: same products, same k-order tree);
// bid<429: yT tile (fp32).
__global__ void __launch_bounds__(512)
k_heavy(const unsigned short* __restrict__ EtHi, const unsigned short* __restrict__ EtLo,
        const unsigned short* __restrict__ PkU,
        unsigned short* __restrict__ GuHi, unsigned short* __restrict__ GuLo,
        float* __restrict__ yT) {
    __shared__ __align__(16) float4 red[512];         // 8 KB
    int tid = threadIdx.x;
    int bid = blockIdx.x;
    int wv = tid >> 6, lane = tid & 63;
    int am = lane & 15, aq = lane >> 4;
    const sh8* Bp = (const sh8*)PkU;
    int k0 = wv * U_KCHUNK, k1 = min(KT_S, k0 + U_KCHUNK);
    f4v acc = {0.f, 0.f, 0.f, 0.f};
    int mt, nt;
    if (bid < HV_GU_END) {
        // triangular decode: bid -> (mt, nt), nt <= mt
        mt = (int)((sqrtf(8.f * (float)bid + 1.f) - 1.f) * 0.5f);
        while ((mt + 1) * (mt + 2) / 2 <= bid) ++mt;
        while (mt * (mt + 1) / 2 > bid) --mt;
        nt = bid - mt * (mt + 1) / 2;
        for (int kt = k0; kt < k1; ++kt) {
            sh8 aa = Bp[(kt * NT_U + mt) * 64 + lane];
            sh8 bb = Bp[(kt * NT_U + nt) * 64 + lane];
            acc = __builtin_amdgcn_mfma_f32_16x16x32_bf16(aa, bb, acc, 0, 0, 0);
        }
    } else {
        // yT[d,u] = sum_s Et[d,s]*B[u,s]  (hi/lo split E)
        int tile = bid - HV_GU_END;
        mt = tile / NT_U; nt = tile % NT_U;
        const unsigned short* rH = EtHi + (size_t)(mt * 16 + am) * SPAD;
        const unsigned short* rL = EtLo + (size_t)(mt * 16 + am) * SPAD;
        for (int kt = k0; kt < k1; ++kt) {
            sh8 bb = Bp[(kt * NT_U + nt) * 64 + lane];
            sh8 ah = *(const sh8*)(rH + kt * 32 + aq * 8);
            sh8 al = *(const sh8*)(rL + kt * 32 + aq * 8);
            acc = __builtin_amdgcn_mfma_f32_16x16x32_bf16(ah, bb, acc, 0, 0, 0);
            acc = __builtin_amdgcn_mfma_f32_16x16x32_bf16(al, bb, acc, 0, 0, 0);
        }
    }
    red[wv * 64 + lane] = make_float4(acc[0], acc[1], acc[2], acc[3]);
    __syncthreads();
    if (wv == 0) {
        float4 v = red[lane];
        #pragma unroll
        for (int w2 = 1; w2 < 8; ++w2) {
            float4 p = red[w2 * 64 + lane];
            v.x += p.x; v.y += p.y; v.z += p.z; v.w += p.w;
        }
        float vr[4] = {v.x, v.y, v.z, v.w};
        if (bid < HV_GU_END) {
            ushort4 mh, ml;
            unsigned short h;
            h = f2bs(vr[0]); mh.x = h; ml.x = f2bs(vr[0] - bu2f(h));
            h = f2bs(vr[1]); mh.y = h; ml.y = f2bs(vr[1] - bu2f(h));
            h = f2bs(vr[2]); mh.z = h; ml.z = f2bs(vr[2] - bu2f(h));
            h = f2bs(vr[3]); mh.w = h; ml.w = f2bs(vr[3] - bu2f(h));
            unsigned short hv[4] = {mh.x, mh.y, mh.z, mh.w};
            unsigned short lv[4] = {ml.x, ml.y, ml.z, ml.w};
            #pragma unroll
            for (int reg = 0; reg < 4; ++reg) {
                size_t idx = (size_t)(mt * 16 + aq * 4 + reg) * UPAD + nt * 16 + am;
                GuHi[idx] = hv[reg];
                GuLo[idx] = lv[reg];
            }
            if (mt != nt) {                           // mirror (contiguous ushort4)
                size_t mi = (size_t)(nt * 16 + am) * UPAD + mt * 16 + aq * 4;
                *(ushort4*)(GuHi + mi) = mh;
                *(ushort4*)(GuLo + mi) = ml;
            }
        } else {
            #pragma unroll
            for (int reg = 0; reg < 4; ++reg)
                yT[(size_t)(mt * 16 + aq * 4 + reg) * UPAD + nt * 16 + am] = vr[reg];
        }
    }
}

// ---------- midA: V = [y*Pc_u | Eu*Pc_i] (352x128 fp32 -> hi/lo B-frags) ----------
__global__ void __launch_bounds__(256)
k_midA(const float* __restrict__ yT, const float* __restrict__ uEt,
       const float* __restrict__ Pc,
       unsigned short* __restrict__ VHi, unsigned short* __restrict__ VLo) {
    int bid = blockIdx.x;                             // 176 = 11 kt * 16 jg
    int kt = bid >> 4, jg = bid & 15;
    int tid = threadIdx.x;
    int kl = tid & 31, jl = tid >> 5;                 // 32 k x 8 j
    int k = kt * 32 + kl;
    int j = jg * 8 + jl;
    const float* S = (j < H_DIM) ? yT : uEt;          // y[k][d]=yT[d][k]; Eu[k][d]=uEt[d][k]
    const float* P = Pc + ((j < H_DIM) ? (size_t)j
                                       : (size_t)(D_DIM * H_DIM + j - H_DIM));
    float acc = 0.f;
    #pragma unroll 8
    for (int d = 0; d < D_DIM; ++d)
        acc = fmaf(S[(size_t)d * UPAD + k], P[(size_t)d * H_DIM], acc);
    unsigned short hi = f2bs(acc);
    unsigned short lo = f2bs(acc - bu2f(hi));
    int kq = (k >> 3) & 3, jj = k & 7;
    int nt = j >> 4, nn = j & 15;
    size_t idx = ((size_t)(kt * 8 + nt) * 64 + kq * 16 + nn) * 8 + jj;
    VHi[idx] = hi;
    VLo[idx] = lo;
}

// ---------- midB: [A_u | w] = Gu x V via MFMA (3-product hi/lo) ----------
__global__ void __launch_bounds__(256)
k_midB(const unsigned short* __restrict__ GuHi, const unsigned short* __restrict__ GuLo,
       const unsigned short* __restrict__ VHi, const unsigned short* __restrict__ VLo,
       const float* __restrict__ Wf, float* __restrict__ A,
       unsigned short* __restrict__ wTH, unsigned short* __restrict__ wTL) {
    int tid = threadIdx.x, wv = tid >> 6, lane = tid & 63;
    int am = lane & 15, aq = lane >> 4;
    int tile = blockIdx.x * 4 + wv;                   // 0..175
    int mt = tile >> 3, nt = tile & 7;
    const sh8* BH = (const sh8*)VHi;
    const sh8* BL = (const sh8*)VLo;
    const unsigned short* rH = GuHi + (size_t)(mt * 16 + am) * UPAD;
    const unsigned short* rL = GuLo + (size_t)(mt * 16 + am) * UPAD;
    f4v acc = {0.f, 0.f, 0.f, 0.f};
    #pragma unroll
    for (int kt = 0; kt < KT_U; ++kt) {
        sh8 bh = BH[(kt * 8 + nt) * 64 + lane];
        sh8 bl = BL[(kt * 8 + nt) * 64 + lane];
        sh8 ah = *(const sh8*)(rH + kt * 32 + aq * 8);
        sh8 al = *(const sh8*)(rL + kt * 32 + aq * 8);
        acc = __builtin_amdgcn_mfma_f32_16x16x32_bf16(ah, bh, acc, 0, 0, 0);
        acc = __builtin_amdgcn_mfma_f32_16x16x32_bf16(ah, bl, acc, 0, 0, 0);
        acc = __builtin_amdgcn_mfma_f32_16x16x32_bf16(al, bh, acc, 0, 0, 0);
    }
    if (nt < 4) {                                     // A_u columns 0..63 (+b1)
        int j = nt * 16 + am;
        float b1j = Wf[WF_B1 + j];
        #pragma unroll
        for (int reg = 0; reg < 4; ++reg) {
            int r = mt * 16 + aq * 4 + reg;
            if (r < U_CNT) A[(size_t)r * H_DIM + j] = acc[reg] + b1j;
        }
    } else {                                          // w columns -> wT hi/lo planes
        int j = nt * 16 + am - 64;
        int r0 = mt * 16 + aq * 4;
        ushort4 vh, vl;
        unsigned short h;
        h = f2bs(acc[0]); vh.x = h; vl.x = f2bs(acc[0] - bu2f(h));
        h = f2bs(acc[1]); vh.y = h; vl.y = f2bs(acc[1] - bu2f(h));
        h = f2bs(acc[2]); vh.z = h; vl.z = f2bs(acc[2] - bu2f(h));
        h = f2bs(acc[3]); vh.w = h; vl.w = f2bs(acc[3] - bu2f(h));
        *(ushort4*)(wTH + (size_t)j * UPAD + r0) = vh;
        *(ushort4*)(wTL + (size_t)j * UPAD + r0) = vl;
    }
}

// ---------- A_s = B^T w via MFMA over PkS; 2 nt per block (ILP x2) ----------
// R6 post-mortem: 365x4-wave grid = 5.7 waves/CU, serial 11-step MFMA chain
// per wave -> latency-starved. 2 nt share the wT A-operand loads: halves wT
// traffic and doubles independent MFMA/load chains per wave.
__global__ void __launch_bounds__(256)
k_as(const unsigned short* __restrict__ wTH, const unsigned short* __restrict__ wTL,
     const unsigned short* __restrict__ PkS, float* __restrict__ A) {
    __shared__ float ls[2][16][65];
    int nt0 = blockIdx.x * 2;                         // 0,2,..,364
    int has2 = (nt0 + 1 < NT_S);
    int tid = threadIdx.x, wv = tid >> 6, lane = tid & 63;
    int am = lane & 15, aq = lane >> 4;
    const sh8* Bp = (const sh8*)PkS;
    const unsigned short* rH = wTH + (size_t)(wv * 16 + am) * UPAD;
    const unsigned short* rL = wTL + (size_t)(wv * 16 + am) * UPAD;
    f4v a0h = {0.f, 0.f, 0.f, 0.f}, a0l = a0h, a1h = a0h, a1l = a0h;
    #pragma unroll
    for (int kt = 0; kt < KT_U; ++kt) {
        sh8 ah = *(const sh8*)(rH + kt * 32 + aq * 8);
        sh8 al = *(const sh8*)(rL + kt * 32 + aq * 8);
        sh8 bb0 = Bp[(kt * NT_S + nt0) * 64 + lane];
        a0h = __builtin_amdgcn_mfma_f32_16x16x32_bf16(ah, bb0, a0h, 0, 0, 0);
        a0l = __builtin_amdgcn_mfma_f32_16x16x32_bf16(al, bb0, a0l, 0, 0, 0);
        if (has2) {
            sh8 bb1 = Bp[(kt * NT_S + nt0 + 1) * 64 + lane];
            a1h = __builtin_amdgcn_mfma_f32_16x16x32_bf16(ah, bb1, a1h, 0, 0, 0);
            a1l = __builtin_amdgcn_mfma_f32_16x16x32_bf16(al, bb1, a1l, 0, 0, 0);
        }
    }
    #pragma unroll
    for (int reg = 0; reg < 4; ++reg) {
        ls[0][am][wv * 16 + aq * 4 + reg] = a0h[reg] + a0l[reg];   // [s_local][j]
        ls[1][am][wv * 16 + aq * 4 + reg] = a1h[reg] + a1l[reg];
    }
    __syncthreads();
    int sl = tid >> 4, j0 = (tid & 15) * 4;
    #pragma unroll
    for (int g = 0; g < 2; ++g) {
        int s = (nt0 + g) * 16 + sl;
        if ((g == 0 || has2) && s < S_CNT) {
            float4 v = make_float4(ls[g][sl][j0], ls[g][sl][j0 + 1],
                                   ls[g][sl][j0 + 2], ls[g][sl][j0 + 3]);
            *(float4*)(A + (size_t)(U_CNT + s) * H_DIM + j0) = v;
        }
    }
}

// ---------- fused MLP via MFMA: persistent + pipelined; DPP reductions ----------
// (no min-waves launch bound: R2 lesson -- it forced spills, 48 VGPR + 800MB scratch)
__global__ void __launch_bounds__(256)
HyperModel_65755949301857_kernel(
      const float* __restrict__ A, const int* __restrict__ userIdx,
      const int* __restrict__ servIdx, const float* __restrict__ Wf,
      const unsigned short* __restrict__ Wb,
      void* __restrict__ out, const void* __restrict__ uE) {
    int tid = threadIdx.x;
    int wv = tid >> 6, lane = tid & 63;
    int isf32 = detect_f32(uE);
    int m = lane & 15, quad = lane >> 4;

    const sh8* Bp = (const sh8*)Wb;
    sh8 b00 = Bp[0 * 64 + lane], b01 = Bp[1 * 64 + lane];
    sh8 b10 = Bp[2 * 64 + lane], b11 = Bp[3 * 64 + lane];
    sh8 b20 = Bp[4 * 64 + lane], b21 = Bp[5 * 64 + lane];
    sh8 b30 = Bp[6 * 64 + lane], b31 = Bp[7 * 64 + lane];
    float b2c0 = Wf[WF_B2 + m],      b2c1 = Wf[WF_B2 + 16 + m];
    float b2c2 = Wf[WF_B2 + 32 + m], b2c3 = Wf[WF_B2 + 48 + m];
    float g2c0 = Wf[WF_G2 + m],      g2c1 = Wf[WF_G2 + 16 + m];
    float g2c2 = Wf[WF_G2 + 32 + m], g2c3 = Wf[WF_G2 + 48 + m];
    float e2c0 = Wf[WF_BE2 + m],      e2c1 = Wf[WF_BE2 + 16 + m];
    float e2c2 = Wf[WF_BE2 + 32 + m], e2c3 = Wf[WF_BE2 + 48 + m];
    float w3c0 = Wf[WF_W3 + m],      w3c1 = Wf[WF_W3 + 16 + m];
    float w3c2 = Wf[WF_W3 + 32 + m], w3c3 = Wf[WF_W3 + 48 + m];
    float b3v = Wf[WF_B3];
    const float* G1l = Wf + WF_G1 + quad * 8;
    const float* BE1l = Wf + WF_BE1 + quad * 8;

    const long TILES = B_CNT / 16;                    // 31250
    const long stride = (long)gridDim.x * 4;
    long tile = (long)blockIdx.x * 4 + wv;
    if (tile >= TILES) return;

    int r0 = (int)(tile * 16 + m);
    const float4* Au = (const float4*)(A + (long)userIdx[r0] * 64);
    const float4* As = (const float4*)(A + (long)(servIdx[r0] + U_CNT) * 64);
    float4 bu0 = Au[quad * 2], bu1 = Au[quad * 2 + 1], bu2 = Au[8 + quad * 2], bu3 = Au[9 + quad * 2];
    float4 bs0 = As[quad * 2], bs1 = As[quad * 2 + 1], bs2 = As[8 + quad * 2], bs3 = As[9 + quad * 2];
    long tn = tile + stride;
    int uin = 0, sin = 0;
    if (tn < TILES) {
        int rn = (int)(tn * 16 + m);
        uin = userIdx[rn];
        sin = servIdx[rn] + U_CNT;
    }

    while (true) {
        float zl[8], zh[8];
        zl[0] = bu0.x + bs0.x; zl[1] = bu0.y + bs0.y; zl[2] = bu0.z + bs0.z; zl[3] = bu0.w + bs0.w;
        zl[4] = bu1.x + bs1.x; zl[5] = bu1.y + bs1.y; zl[6] = bu1.z + bs1.z; zl[7] = bu1.w + bs1.w;
        zh[0] = bu2.x + bs2.x; zh[1] = bu2.y + bs2.y; zh[2] = bu2.z + bs2.z; zh[3] = bu2.w + bs2.w;
        zh[4] = bu3.x + bs3.x; zh[5] = bu3.y + bs3.y; zh[6] = bu3.z + bs3.z; zh[7] = bu3.w + bs3.w;

        long tcur = tile;
        bool have_next = (tn < TILES);
        if (have_next) {
            const float4* Au2 = (const float4*)(A + (long)uin * 64);
            const float4* As2 = (const float4*)(A + (long)sin * 64);
            bu0 = Au2[quad * 2]; bu1 = Au2[quad * 2 + 1]; bu2 = Au2[8 + quad * 2]; bu3 = Au2[9 + quad * 2];
            bs0 = As2[quad * 2]; bs1 = As2[quad * 2 + 1]; bs2 = As2[8 + quad * 2]; bs3 = As2[9 + quad * 2];
            long tnn = tn + stride;
            if (tnn < TILES) {
                int rnn = (int)(tnn * 16 + m);
                uin = userIdx[rnn];
                sin = servIdx[rnn] + U_CNT;
            }
            tile = tn;
            tn = tnn;
        }

        float s = 0.f, q = 0.f;
        #pragma unroll
        for (int j = 0; j < 8; ++j) {
            s += zl[j] + zh[j];
            q = fmaf(zl[j], zl[j], q);
            q = fmaf(zh[j], zh[j], q);
        }
        s += __shfl_xor(s, 16, 64); s += __shfl_xor(s, 32, 64);
        q += __shfl_xor(q, 16, 64); q += __shfl_xor(q, 32, 64);
        float mu = s * (1.f / 64.f);
        float rs = rsqrtf(q * (1.f / 64.f) - mu * mu + LN_EPS);
        float nm = -mu * rs;

        sh8 a0, a1;
        #pragma unroll
        for (int j = 0; j < 8; ++j) {
            float h0 = fmaxf(fmaf(fmaf(zl[j], rs, nm), G1l[j],      BE1l[j]),      0.f);
            float h1 = fmaxf(fmaf(fmaf(zh[j], rs, nm), G1l[32 + j], BE1l[32 + j]), 0.f);
            a0[j] = (short)f2bs(h0);
            a1[j] = (short)f2bs(h1);
        }

        f4v acc0 = {0.f, 0.f, 0.f, 0.f}, acc1 = acc0, acc2 = acc0, acc3 = acc0;
        acc0 = __builtin_amdgcn_mfma_f32_16x16x32_bf16(a0, b00, acc0, 0, 0, 0);
        acc0 = __builtin_amdgcn_mfma_f32_16x16x32_bf16(a1, b01, acc0, 0, 0, 0);
        acc1 = __builtin_amdgcn_mfma_f32_16x16x32_bf16(a0, b10, acc1, 0, 0, 0);
        acc1 = __builtin_amdgcn_mfma_f32_16x16x32_bf16(a1, b11, acc1, 0, 0, 0);
        acc2 = __builtin_amdgcn_mfma_f32_16x16x32_bf16(a0, b20, acc2, 0, 0, 0);
        acc2 = __builtin_amdgcn_mfma_f32_16x16x32_bf16(a1, b21, acc2, 0, 0, 0);
        acc3 = __builtin_amdgcn_mfma_f32_16x16x32_bf16(a0, b30, acc3, 0, 0, 0);
        acc3 = __builtin_amdgcn_mfma_f32_16x16x32_bf16(a1, b31, acc3, 0, 0, 0);

        float y0[4], y1[4], y2[4], y3[4];
        float srow[4], qrow[4];
        #pragma unroll
        for (int reg = 0; reg < 4; ++reg) {
            y0[reg] = acc0[reg] + b2c0;
            y1[reg] = acc1[reg] + b2c1;
            y2[reg] = acc2[reg] + b2c2;
            y3[reg] = acc3[reg] + b2c3;
            srow[reg] = (y0[reg] + y1[reg]) + (y2[reg] + y3[reg]);
            float qa = y0[reg] * y0[reg];
            qa = fmaf(y1[reg], y1[reg], qa);
            qa = fmaf(y2[reg], y2[reg], qa);
            qa = fmaf(y3[reg], y3[reg], qa);
            qrow[reg] = qa;
        }
        #pragma unroll
        for (int reg = 0; reg < 4; ++reg) {           // DPP: 16-lane sums, no LDS
            srow[reg] = rowsum16(srow[reg]);
            qrow[reg] = rowsum16(qrow[reg]);
        }
        float o[4];
        #pragma unroll
        for (int reg = 0; reg < 4; ++reg) {
            float mu2 = srow[reg] * (1.f / 64.f);
            float rs2 = rsqrtf(qrow[reg] * (1.f / 64.f) - mu2 * mu2 + LN_EPS);
            float nm2 = -mu2 * rs2;
            float t0 = fmaxf(fmaf(fmaf(y0[reg], rs2, nm2), g2c0, e2c0), 0.f);
            float t1 = fmaxf(fmaf(fmaf(y1[reg], rs2, nm2), g2c1, e2c1), 0.f);
            float t2 = fmaxf(fmaf(fmaf(y2[reg], rs2, nm2), g2c2, e2c2), 0.f);
            float t3 = fmaxf(fmaf(fmaf(y3[reg], rs2, nm2), g2c3, e2c3), 0.f);
            o[reg] = fmaf(t0, w3c0, fmaf(t1, w3c1, fmaf(t2, w3c2, t3 * w3c3)));
        }
        #pragma unroll
        for (int reg = 0; reg < 4; ++reg) o[reg] = rowsum16(o[reg]);
        if (m == 0) {
            long rb = tcur * 16 + quad * 4;
            if (isf32) {
                float4 v = make_float4(o[0] + b3v, o[1] + b3v, o[2] + b3v, o[3] + b3v);
                *(float4*)((float*)out + rb) = v;
            } else {
                ushort4 v;
                v.x = f2bs(o[0] + b3v);
                v.y = f2bs(o[1] + b3v);
                v.z = f2bs(o[2] + b3v);
                v.w = f2bs(o[3] + b3v);
                *(ushort4*)((bf16*)out + rb) = v;
            }
        }
        if (!have_next) break;
    }
}

extern "C" __attribute__((visibility("default")))
void kernel_launch(void* const* d_in, const int* in_sizes, int n_in,
                   void* d_out, int out_size, void* d_ws, size_t ws_size,
                   hipStream_t stream) {
    const void* uE   = d_in[0];
    const void* iE   = d_in[1];
    const void* uHy  = d_in[2];
    const void* iHy  = d_in[3];
    const void* W1   = d_in[4];
    const void* b1   = d_in[5];
    const void* g1   = d_in[6];
    const void* be1  = d_in[7];
    const void* W2   = d_in[8];
    const void* b2   = d_in[9];
    const void* g2   = d_in[10];
    const void* be2  = d_in[11];
    const void* W3   = d_in[12];
    const void* b3   = d_in[13];
    const void* adj_vals = d_in[14];
    const int*  adj_rows = (const int*)d_in[15];
    const int*  adj_cols = (const int*)d_in[16];
    const int*  userIdx  = (const int*)d_in[17];
    const int*  servIdx  = (const int*)d_in[18];

    char* w = (char*)d_ws;
    size_t off = 0;
    auto alloc = [&](size_t bytes) -> char* {
        char* p = w + off;
        off += (bytes + 255) & ~(size_t)255;
        return p;
    };
    unsigned short* EtHi = (unsigned short*)alloc((size_t)ET_U16 * 2);
    unsigned short* EtLo = (unsigned short*)alloc((size_t)ET_U16 * 2);
    unsigned short* GuHi = (unsigned short*)alloc((size_t)GU_U16 * 2);
    unsigned short* GuLo = (unsigned short*)alloc((size_t)GU_U16 * 2);
    unsigned short* VHi  = (unsigned short*)alloc((size_t)V_U16 * 2);
    unsigned short* VLo  = (unsigned short*)alloc((size_t)V_U16 * 2);
    unsigned short* wTH  = (unsigned short*)alloc((size_t)WT_U16 * 2);
    unsigned short* wTL  = (unsigned short*)alloc((size_t)WT_U16 * 2);
    float* yT   = (float*)alloc((size_t)D_DIM * UPAD * 4);
    float* uEt  = (float*)alloc((size_t)D_DIM * UPAD * 4);
    float* Pc   = (float*)alloc((size_t)2 * D_DIM * H_DIM * 4);
    float* A    = (float*)alloc((size_t)N_CNT * H_DIM * 4);
    float* Wf   = (float*)alloc((size_t)WF_TOT * 4);
    unsigned short* Wb = (unsigned short*)alloc((size_t)4096 * 2);
    // zero-init span: PkS+PkU contiguous (edge-pack pads must be 0 each run)
    unsigned short* PkS = (unsigned short*)alloc((size_t)PKS_U16 * 2);
    unsigned short* PkU = (unsigned short*)alloc((size_t)PKU_U16 * 2);
    size_t zspan = (size_t)((char*)(PkU + PKU_U16) - (char*)PkS);

    hipMemsetAsync(PkS, 0, zspan, stream);
    k_pre<<<PRE_UNITS, 256, 0, stream>>>(iE, EtHi, EtLo, adj_rows, adj_cols,
                                         adj_vals, PkS, PkU, uEt,
                                         uHy, iHy, W1, W2, b1, g1, be1,
                                         b2, g2, be2, W3, b3, Pc, Wf, Wb, uE);
    k_heavy<<<HV_BLOCKS, 512, 0, stream>>>(EtHi, EtLo, PkU, GuHi, GuLo, yT);
    k_midA<<<176, 256, 0, stream>>>(yT, uEt, Pc, VHi, VLo);
    k_midB<<<44, 256, 0, stream>>>(GuHi, GuLo, VHi, VLo, Wf, A, wTH, wTL);
    k_as<<<183, 256, 0, stream>>>(wTH, wTL, PkS, A);
    HyperModel_65755949301857_kernel<<<MLP_BLOCKS, 256, 0, stream>>>(
        A, userIdx, servIdx, Wf, Wb, d_out, uE);
}

// Round 8
// 186.053 us; speedup vs baseline: 1.0059x; 1.0059x over previous
//
#include <hip/hip_runtime.h>
#include <hip/hip_bf16.h>

#define U_CNT 339
#define S_CNT 5825
#define N_CNT 6164          // U + S
#define D_DIM 128
#define R_DIM 32
#define B_CNT 500000
#define NNZ_U 200000        // edges with u-row (first half of rows=concat(u,s))
#define H_DIM 64
#define LN_EPS 1e-5f

// ---- padded dims ----
#define SPAD 5856           // 183*32  (s padded to K-granularity 32)
#define UPAD 352            // 11*32   (u padded)
#define KT_S 183            // s as K: 5856/32
#define KT_U 11             // u as K: 352/32
#define NT_S 365            // s as N: 5840/16 (>= 5825)
#define NT_U 22             // u as N: 352/16
#define U_KCHUNK 23         // 8*23 = 184 >= 183 (8-way split-K)

#define ET_U16 (D_DIM * SPAD)          // s-side E^T plane (ushorts)
#define PKS_U16 (KT_U * NT_S * 512)    // B packed [k=u][n=s] MFMA B-frags
#define PKU_U16 (KT_S * NT_U * 512)    // B packed [k=s][n=u] MFMA B-frags
#define WT_U16  (H_DIM * UPAD)         // w^T [j][u] hi/lo planes
#define GU_U16  (UPAD * UPAD)          // Gu hi/lo planes, row-major
#define V_U16   (KT_U * 8 * 512)       // V = [y*Pc_u | Eu*Pc_i] as B-frags (352x128)

// k_pre units: 183 s-transpose + 11 u-transpose + 782 edge-pack + 9 Pc/weight
#define PRE_S_UNITS 183
#define PRE_U_UNITS 11
#define PRE_UT_END (PRE_S_UNITS + PRE_U_UNITS)            // 194
#define PRE_EDGE_UNITS ((NNZ_U + 255) / 256)              // 782
#define PRE_EDGE_END (PRE_UT_END + PRE_EDGE_UNITS)        // 976
#define PRE_UNITS (PRE_EDGE_END + 9)                      // 985

// k_heavy roles: 253 triangular GU tiles + 176 yT tiles, 512 thr
#define HV_GU_END 253                  // 22*23/2 (Gu symmetric)
#define HV_YT_END 429
#define HV_BLOCKS 429

// fp32 weight-block offsets (elements)
#define WF_B1   4096
#define WF_G1   4160
#define WF_BE1  4224
#define WF_B2   4288
#define WF_G2   4352
#define WF_BE2  4416
#define WF_W3   4480
#define WF_B3   4544
#define WF_TOT  4545

// MLP grid: 1024 DEFINITIVE. Measured 44.5-44.8us at 1024 (R5,R6) vs
// 52.0us at 1280 post-DPP (R7) and 58.6 pre-DPP (R4). Gather/TCP-bound:
// extra residency adds L1 contention, does not hide latency.
#define MLP_BLOCKS 1024

typedef __hip_bfloat16 bf16;
typedef __attribute__((ext_vector_type(8))) short sh8;   // 8 bf16 (MFMA A/B frag)
typedef __attribute__((ext_vector_type(4))) float f4v;   // MFMA C/D frag

__device__ __forceinline__ float b2f(bf16 x) { return __bfloat162float(x); }
__device__ __forceinline__ unsigned short f2bs(float f) {
    union { bf16 b; unsigned short s; } u;
    u.b = __float2bfloat16(f);
    return u.s;
}
__device__ __forceinline__ float bu2f(unsigned int lo16) {   // bf16 bits -> f32
    return __uint_as_float(lo16 << 16);
}
__device__ __forceinline__ float ldf(const void* p, long i, int isf32) {
    return isf32 ? ((const float*)p)[i] : b2f(((const bf16*)p)[i]);
}
// per-wave dtype detect (no flag buffer, no extra launch); wave-uniform result
__device__ __forceinline__ int detect_f32(const void* uE) {
    const unsigned short* p = (const unsigned short*)uE;
    int lane = threadIdx.x & 63;
    unsigned short v = p[2 * lane];
    int e = (v >> 7) & 0xFF;
    unsigned long long m = __ballot(e >= 127);
    return (m != 0ull) ? 1 : 0;
}

// ---- DPP within-16-lane sum reduction (pure VALU, no LDS pipe) ----
// R4->R5 verified: replacing 48 __shfl_xor with DPP cut MLP 58.6->44.8us.
template<int CTRL>
__device__ __forceinline__ float dpp_add(float x) {
    int t = __builtin_amdgcn_update_dpp(0, __float_as_int(x), CTRL, 0xF, 0xF, false);
    return x + __int_as_float(t);
}
__device__ __forceinline__ float rowsum16(float x) {
    x = dpp_add<0xB1>(x);    // quad_perm [1,0,3,2]  (xor 1)
    x = dpp_add<0x4E>(x);    // quad_perm [2,3,0,1]  (xor 2)
    x = dpp_add<0x124>(x);   // row_ror:4
    x = dpp_add<0x128>(x);   // row_ror:8
    return x;
}

// ---- vectorized 16-element row-chunk load (R7 post-mortem: Common-mistake #2,
// the scalar ldf loop in transpose roles was 16x 2B loads per thread) ----
__device__ __forceinline__ void load16(const void* p, size_t elem0, int isf32,
                                       float* dst) {
    if (isf32) {
        const float4* p4 = (const float4*)((const float*)p + elem0);
        float4 v0 = p4[0], v1 = p4[1], v2 = p4[2], v3 = p4[3];
        dst[0] = v0.x;  dst[1] = v0.y;  dst[2] = v0.z;  dst[3] = v0.w;
        dst[4] = v1.x;  dst[5] = v1.y;  dst[6] = v1.z;  dst[7] = v1.w;
        dst[8] = v2.x;  dst[9] = v2.y;  dst[10] = v2.z; dst[11] = v2.w;
        dst[12] = v3.x; dst[13] = v3.y; dst[14] = v3.z; dst[15] = v3.w;
    } else {
        const sh8* p8 = (const sh8*)((const unsigned short*)p + elem0);
        sh8 u0 = p8[0], u1 = p8[1];
        #pragma unroll
        for (int j = 0; j < 8; ++j) {
            dst[j]     = bu2f((unsigned short)u0[j]);
            dst[8 + j] = bu2f((unsigned short)u1[j]);
        }
    }
}

// ---------- pre: s-transpose | u-transpose | edge pack | Pc/weight prep ----------
__global__ void __launch_bounds__(256)
k_pre(const void* __restrict__ iE,
      unsigned short* __restrict__ EtHi, unsigned short* __restrict__ EtLo,
      const int* __restrict__ rows, const int* __restrict__ cols,
      const void* __restrict__ vals,
      unsigned short* __restrict__ PkS, unsigned short* __restrict__ PkU,
      float* __restrict__ uEt,
      const void* __restrict__ uHy, const void* __restrict__ iHy,
      const void* __restrict__ W1, const void* __restrict__ W2,
      const void* __restrict__ b1, const void* __restrict__ g1,
      const void* __restrict__ be1, const void* __restrict__ b2,
      const void* __restrict__ g2, const void* __restrict__ be2,
      const void* __restrict__ W3, const void* __restrict__ b3,
      float* __restrict__ Pc, float* __restrict__ Wf,
      unsigned short* __restrict__ Wb,
      const void* __restrict__ uE) {
    __shared__ __align__(16) float sm[6688];          // 26.7 KB arena (max role)
    int tid = threadIdx.x;
    int isf32 = detect_f32(uE);
    int unit = blockIdx.x;
    if (unit < PRE_S_UNITS) {                         // s-node transpose role
        float* ls = sm;                               // [32][129]
        int sg0 = unit * 32;
        int nl = tid >> 3, dbase = (tid & 7) * 16;
        int s = sg0 + nl;
        float tmp[16];
        if (s < S_CNT) {
            load16(iE, (size_t)s * D_DIM + dbase, isf32, tmp);
        } else {
            #pragma unroll
            for (int i = 0; i < 16; ++i) tmp[i] = 0.f;
        }
        #pragma unroll
        for (int i = 0; i < 16; ++i) ls[nl * 129 + dbase + i] = tmp[i];
        __syncthreads();
        int nl2 = tid & 31;
        int s2 = sg0 + nl2;
        #pragma unroll
        for (int i = 0; i < 16; ++i) {
            int d = (tid >> 5) * 16 + i;
            float v = ls[nl2 * 129 + d];
            unsigned short hi = f2bs(v);
            unsigned short lo = f2bs(v - bu2f(hi));
            EtHi[(size_t)d * SPAD + s2] = hi;
            EtLo[(size_t)d * SPAD + s2] = lo;
        }
    } else if (unit < PRE_UT_END) {                   // u-node transpose (f32 out)
        float* ls = sm;
        int ug0 = (unit - PRE_S_UNITS) * 32;
        int nl = tid >> 3, dbase = (tid & 7) * 16;
        int u = ug0 + nl;
        float tmp[16];
        if (u < U_CNT) {
            load16(uE, (size_t)u * D_DIM + dbase, isf32, tmp);
        } else {
            #pragma unroll
            for (int i = 0; i < 16; ++i) tmp[i] = 0.f;
        }
        #pragma unroll
        for (int i = 0; i < 16; ++i) ls[nl * 129 + dbase + i] = tmp[i];
        __syncthreads();
        int nl2 = tid & 31;
        int u2 = ug0 + nl2;
        #pragma unroll
        for (int i = 0; i < 16; ++i) {
            int d = (tid >> 5) * 16 + i;
            uEt[(size_t)d * UPAD + u2] = ls[nl2 * 129 + d];
        }
    } else if (unit < PRE_EDGE_END) {                 // edge pack (u-rows only)
        int e = (unit - PRE_UT_END) * 256 + tid;
        if (e < NNZ_U) {
            int r = rows[e];
            if (r < U_CNT) {
                int u = r, s = cols[e] - U_CNT;
                unsigned short w = f2bs(ldf(vals, e, isf32));
                int kt = u >> 5, kq = (u >> 3) & 3, j = u & 7;
                int nt = s >> 4, nn = s & 15;
                PkS[((kt * NT_S + nt) * 64 + kq * 16 + nn) * 8 + j] = w;
                int kt2 = s >> 5, kq2 = (s >> 3) & 3, j2 = s & 7;
                int nt2 = u >> 4, nn2 = u & 15;
                PkU[((kt2 * NT_U + nt2) * 64 + kq2 * 16 + nn2) * 8 + j2] = w;
            }
        }
    } else {                                          // Pc / weight prep roles
        int rb = unit - PRE_EDGE_END;                 // 0..8
        if (rb == 8) {                                // weight prep
            for (int i = tid; i < 4096; i += 256) {
                int j = i & 7, lane = (i >> 3) & 63, kh = (i >> 9) & 1, t = i >> 10;
                int k = kh * 32 + ((lane >> 4) & 3) * 8 + j;
                int n = t * 16 + (lane & 15);
                Wb[i] = f2bs(ldf(W2, k * 64 + n, isf32));
            }
            for (int i = tid; i < WF_TOT - 4096; i += 256) {
                int g = 4096 + i;
                float v;
                if      (g < WF_G1)  v = ldf(b1,  g - WF_B1,   isf32);
                else if (g < WF_BE1) v = ldf(g1,  g - WF_G1,   isf32);
                else if (g < WF_B2)  v = ldf(be1, g - WF_BE1,  isf32);
                else if (g < WF_G2)  v = ldf(b2,  g - WF_B2,   isf32);
                else if (g < WF_BE2) v = ldf(g2,  g - WF_G2,   isf32);
                else if (g < WF_W3)  v = ldf(be2, g - WF_BE2,  isf32);
                else if (g < WF_B3)  v = ldf(W3,  g - WF_W3,   isf32);
                else                 v = ldf(b3,  0,           isf32);
                Wf[g] = v;
            }
            return;
        }
        int side = rb >> 2;                           // 0 = user, 1 = service
        int j0 = (rb & 3) * 16;                       // 16 Pc-columns per block
        const void* Hy = side ? iHy : uHy;            // [32][128]
        long wbase = (long)side * D_DIM * H_DIM;
        float* Hs = sm;                               // [32][129]
        float* Ws = sm + R_DIM * 129;                 // [128][16]
        float* Ts = Ws + D_DIM * 16;                  // [32][16]
        if (isf32) {
            const float* H = (const float*)Hy;
            for (int i = tid; i < R_DIM * D_DIM; i += 256)
                Hs[(i >> 7) * 129 + (i & 127)] = H[i];
            const float* Wp = (const float*)W1 + wbase;
            for (int i = tid; i < D_DIM * 16; i += 256)
                Ws[i] = Wp[(i >> 4) * H_DIM + j0 + (i & 15)];
        } else {
            const unsigned short* H = (const unsigned short*)Hy;
            for (int i = tid; i < R_DIM * D_DIM; i += 256)
                Hs[(i >> 7) * 129 + (i & 127)] = bu2f(H[i]);
            const unsigned short* Wp = (const unsigned short*)W1 + wbase;
            for (int i = tid; i < D_DIM * 16; i += 256)
                Ws[i] = bu2f(Wp[(i >> 4) * H_DIM + j0 + (i & 15)]);
        }
        __syncthreads();
        for (int idx = tid; idx < R_DIM * 16; idx += 256) {
            int a = idx >> 4, j = idx & 15;
            float acc = 0.f;
            #pragma unroll 8
            for (int d = 0; d < D_DIM; ++d)
                acc = fmaf(Hs[a * 129 + d], Ws[d * 16 + j], acc);
            Ts[idx] = acc;
        }
        __syncthreads();
        for (int idx = tid; idx < D_DIM * 16; idx += 256) {
            int d = idx >> 4, j = idx & 15;
            float acc = 0.f;
            #pragma unroll
            for (int a = 0; a < R_DIM; ++a)
                acc = fmaf(Hs[a * 129 + d], Ts[a * 16 + j], acc);
            Pc[side * D_DIM * H_DIM + d * H_DIM + j0 + j] = acc;
        }
    }
}

// ---------- heavy: 512 threads, 8-way split-K per tile ----------
// bid<253: triangular Gu tile (mt>=nt; symmetric -> mirror write; bitwise
// identical to computing the mirror tile); bid<429: yT tile (fp32).
__global__ void __launch_bounds__(512)
k_heavy(const unsigned short* __restrict__ EtHi, const unsigned short* __restrict__ EtLo,
        const unsigned short* __restrict__ PkU,
        unsigned short* __restrict__ GuHi, unsigned short* __restrict__ GuLo,
        float* __restrict__ yT) {
    __shared__ __align__(16) float4 red[512];         // 8 KB
    int tid = threadIdx.x;
    int bid = blockIdx.x;
    int wv = tid >> 6, lane = tid & 63;
    int am = lane & 15, aq = lane >> 4;
    const sh8* Bp = (const sh8*)PkU;
    int k0 = wv * U_KCHUNK, k1 = min(KT_S, k0 + U_KCHUNK);
    f4v acc = {0.f, 0.f, 0.f, 0.f};
    int mt, nt;
    if (bid < HV_GU_END) {
        // triangular decode: bid -> (mt, nt), nt <= mt
        mt = (int)((sqrtf(8.f * (float)bid + 1.f) - 1.f) * 0.5f);
        while ((mt + 1) * (mt + 2) / 2 <= bid) ++mt;
        while (mt * (mt + 1) / 2 > bid) --mt;
        nt = bid - mt * (mt + 1) / 2;
        for (int kt = k0; kt < k1; ++kt) {
            sh8 aa = Bp[(kt * NT_U + mt) * 64 + lane];
            sh8 bb = Bp[(kt * NT_U + nt) * 64 + lane];
            acc = __builtin_amdgcn_mfma_f32_16x16x32_bf16(aa, bb, acc, 0, 0, 0);
        }
    } else {
        // yT[d,u] = sum_s Et[d,s]*B[u,s]  (hi/lo split E)
        int tile = bid - HV_GU_END;
        mt = tile / NT_U; nt = tile % NT_U;
        const unsigned short* rH = EtHi + (size_t)(mt * 16 + am) * SPAD;
        const unsigned short* rL = EtLo + (size_t)(mt * 16 + am) * SPAD;
        for (int kt = k0; kt < k1; ++kt) {
            sh8 bb = Bp[(kt * NT_U + nt) * 64 + lane];
            sh8 ah = *(const sh8*)(rH + kt * 32 + aq * 8);
            sh8 al = *(const sh8*)(rL + kt * 32 + aq * 8);
            acc = __builtin_amdgcn_mfma_f32_16x16x32_bf16(ah, bb, acc, 0, 0, 0);
            acc = __builtin_amdgcn_mfma_f32_16x16x32_bf16(al, bb, acc, 0, 0, 0);
        }
    }
    red[wv * 64 + lane] = make_float4(acc[0], acc[1], acc[2], acc[3]);
    __syncthreads();
    if (wv == 0) {
        float4 v = red[lane];
        #pragma unroll
        for (int w2 = 1; w2 < 8; ++w2) {
            float4 p = red[w2 * 64 + lane];
            v.x += p.x; v.y += p.y; v.z += p.z; v.w += p.w;
        }
        float vr[4] = {v.x, v.y, v.z, v.w};
        if (bid < HV_GU_END) {
            ushort4 mh, ml;
            unsigned short h;
            h = f2bs(vr[0]); mh.x = h; ml.x = f2bs(vr[0] - bu2f(h));
            h = f2bs(vr[1]); mh.y = h; ml.y = f2bs(vr[1] - bu2f(h));
            h = f2bs(vr[2]); mh.z = h; ml.z = f2bs(vr[2] - bu2f(h));
            h = f2bs(vr[3]); mh.w = h; ml.w = f2bs(vr[3] - bu2f(h));
            unsigned short hv[4] = {mh.x, mh.y, mh.z, mh.w};
            unsigned short lv[4] = {ml.x, ml.y, ml.z, ml.w};
            #pragma unroll
            for (int reg = 0; reg < 4; ++reg) {
                size_t idx = (size_t)(mt * 16 + aq * 4 + reg) * UPAD + nt * 16 + am;
                GuHi[idx] = hv[reg];
                GuLo[idx] = lv[reg];
            }
            if (mt != nt) {                           // mirror (contiguous ushort4)
                size_t mi = (size_t)(nt * 16 + am) * UPAD + mt * 16 + aq * 4;
                *(ushort4*)(GuHi + mi) = mh;
                *(ushort4*)(GuLo + mi) = ml;
            }
        } else {
            #pragma unroll
            for (int reg = 0; reg < 4; ++reg)
                yT[(size_t)(mt * 16 + aq * 4 + reg) * UPAD + nt * 16 + am] = vr[reg];
        }
    }
}

// ---------- midA: V = [y*Pc_u | Eu*Pc_i] (352x128 fp32 -> hi/lo B-frags) ----------
__global__ void __launch_bounds__(256)
k_midA(const float* __restrict__ yT, const float* __restrict__ uEt,
       const float* __restrict__ Pc,
       unsigned short* __restrict__ VHi, unsigned short* __restrict__ VLo) {
    int bid = blockIdx.x;                             // 176 = 11 kt * 16 jg
    int kt = bid >> 4, jg = bid & 15;
    int tid = threadIdx.x;
    int kl = tid & 31, jl = tid >> 5;                 // 32 k x 8 j
    int k = kt * 32 + kl;
    int j = jg * 8 + jl;
    const float* S = (j < H_DIM) ? yT : uEt;          // y[k][d]=yT[d][k]; Eu[k][d]=uEt[d][k]
    const float* P = Pc + ((j < H_DIM) ? (size_t)j
                                       : (size_t)(D_DIM * H_DIM + j - H_DIM));
    float acc = 0.f;
    #pragma unroll 8
    for (int d = 0; d < D_DIM; ++d)
        acc = fmaf(S[(size_t)d * UPAD + k], P[(size_t)d * H_DIM], acc);
    unsigned short hi = f2bs(acc);
    unsigned short lo = f2bs(acc - bu2f(hi));
    int kq = (k >> 3) & 3, jj = k & 7;
    int nt = j >> 4, nn = j & 15;
    size_t idx = ((size_t)(kt * 8 + nt) * 64 + kq * 16 + nn) * 8 + jj;
    VHi[idx] = hi;
    VLo[idx] = lo;
}

// ---------- midB: [A_u | w] = Gu x V via MFMA (3-product hi/lo) ----------
__global__ void __launch_bounds__(256)
k_midB(const unsigned short* __restrict__ GuHi, const unsigned short* __restrict__ GuLo,
       const unsigned short* __restrict__ VHi, const unsigned short* __restrict__ VLo,
       const float* __restrict__ Wf, float* __restrict__ A,
       unsigned short* __restrict__ wTH, unsigned short* __restrict__ wTL) {
    int tid = threadIdx.x, wv = tid >> 6, lane = tid & 63;
    int am = lane & 15, aq = lane >> 4;
    int tile = blockIdx.x * 4 + wv;                   // 0..175
    int mt = tile >> 3, nt = tile & 7;
    const sh8* BH = (const sh8*)VHi;
    const sh8* BL = (const sh8*)VLo;
    const unsigned short* rH = GuHi + (size_t)(mt * 16 + am) * UPAD;
    const unsigned short* rL = GuLo + (size_t)(mt * 16 + am) * UPAD;
    f4v acc = {0.f, 0.f, 0.f, 0.f};
    #pragma unroll
    for (int kt = 0; kt < KT_U; ++kt) {
        sh8 bh = BH[(kt * 8 + nt) * 64 + lane];
        sh8 bl = BL[(kt * 8 + nt) * 64 + lane];
        sh8 ah = *(const sh8*)(rH + kt * 32 + aq * 8);
        sh8 al = *(const sh8*)(rL + kt * 32 + aq * 8);
        acc = __builtin_amdgcn_mfma_f32_16x16x32_bf16(ah, bh, acc, 0, 0, 0);
        acc = __builtin_amdgcn_mfma_f32_16x16x32_bf16(ah, bl, acc, 0, 0, 0);
        acc = __builtin_amdgcn_mfma_f32_16x16x32_bf16(al, bh, acc, 0, 0, 0);
    }
    if (nt < 4) {                                     // A_u columns 0..63 (+b1)
        int j = nt * 16 + am;
        float b1j = Wf[WF_B1 + j];
        #pragma unroll
        for (int reg = 0; reg < 4; ++reg) {
            int r = mt * 16 + aq * 4 + reg;
            if (r < U_CNT) A[(size_t)r * H_DIM + j] = acc[reg] + b1j;
        }
    } else {                                          // w columns -> wT hi/lo planes
        int j = nt * 16 + am - 64;
        int r0 = mt * 16 + aq * 4;
        ushort4 vh, vl;
        unsigned short h;
        h = f2bs(acc[0]); vh.x = h; vl.x = f2bs(acc[0] - bu2f(h));
        h = f2bs(acc[1]); vh.y = h; vl.y = f2bs(acc[1] - bu2f(h));
        h = f2bs(acc[2]); vh.z = h; vl.z = f2bs(acc[2] - bu2f(h));
        h = f2bs(acc[3]); vh.w = h; vl.w = f2bs(acc[3] - bu2f(h));
        *(ushort4*)(wTH + (size_t)j * UPAD + r0) = vh;
        *(ushort4*)(wTL + (size_t)j * UPAD + r0) = vl;
    }
}

// ---------- A_s = B^T w via MFMA over PkS; 2 nt per block (ILP x2) ----------
__global__ void __launch_bounds__(256)
k_as(const unsigned short* __restrict__ wTH, const unsigned short* __restrict__ wTL,
     const unsigned short* __restrict__ PkS, float* __restrict__ A) {
    __shared__ float ls[2][16][65];
    int nt0 = blockIdx.x * 2;                         // 0,2,..,364
    int has2 = (nt0 + 1 < NT_S);
    int tid = threadIdx.x, wv = tid >> 6, lane = tid & 63;
    int am = lane & 15, aq = lane >> 4;
    const sh8* Bp = (const sh8*)PkS;
    const unsigned short* rH = wTH + (size_t)(wv * 16 + am) * UPAD;
    const unsigned short* rL = wTL + (size_t)(wv * 16 + am) * UPAD;
    f4v a0h = {0.f, 0.f, 0.f, 0.f}, a0l = a0h, a1h = a0h, a1l = a0h;
    #pragma unroll
    for (int kt = 0; kt < KT_U; ++kt) {
        sh8 ah = *(const sh8*)(rH + kt * 32 + aq * 8);
        sh8 al = *(const sh8*)(rL + kt * 32 + aq * 8);
        sh8 bb0 = Bp[(kt * NT_S + nt0) * 64 + lane];
        a0h = __builtin_amdgcn_mfma_f32_16x16x32_bf16(ah, bb0, a0h, 0, 0, 0);
        a0l = __builtin_amdgcn_mfma_f32_16x16x32_bf16(al, bb0, a0l, 0, 0, 0);
        if (has2) {
            sh8 bb1 = Bp[(kt * NT_S + nt0 + 1) * 64 + lane];
            a1h = __builtin_amdgcn_mfma_f32_16x16x32_bf16(ah, bb1, a1h, 0, 0, 0);
            a1l = __builtin_amdgcn_mfma_f32_16x16x32_bf16(al, bb1, a1l, 0, 0, 0);
        }
    }
    #pragma unroll
    for (int reg = 0; reg < 4; ++reg) {
        ls[0][am][wv * 16 + aq * 4 + reg] = a0h[reg] + a0l[reg];   // [s_local][j]
        ls[1][am][wv * 16 + aq * 4 + reg] = a1h[reg] + a1l[reg];
    }
    __syncthreads();
    int sl = tid >> 4, j0 = (tid & 15) * 4;
    #pragma unroll
    for (int g = 0; g < 2; ++g) {
        int s = (nt0 + g) * 16 + sl;
        if ((g == 0 || has2) && s < S_CNT) {
            float4 v = make_float4(ls[g][sl][j0], ls[g][sl][j0 + 1],
                                   ls[g][sl][j0 + 2], ls[g][sl][j0 + 3]);
            *(float4*)(A + (size_t)(U_CNT + s) * H_DIM + j0) = v;
        }
    }
}

// ---------- fused MLP via MFMA: persistent + pipelined; DPP reductions ----------
// (no min-waves launch bound: R2 lesson -- it forced spills, 48 VGPR + 800MB scratch)
__global__ void __launch_bounds__(256)
HyperModel_65755949301857_kernel(
      const float* __restrict__ A, const int* __restrict__ userIdx,
      const int* __restrict__ servIdx, const float* __restrict__ Wf,
      const unsigned short* __restrict__ Wb,
      void* __restrict__ out, const void* __restrict__ uE) {
    int tid = threadIdx.x;
    int wv = tid >> 6, lane = tid & 63;
    int isf32 = detect_f32(uE);
    int m = lane & 15, quad = lane >> 4;

    const sh8* Bp = (const sh8*)Wb;
    sh8 b00 = Bp[0 * 64 + lane], b01 = Bp[1 * 64 + lane];
    sh8 b10 = Bp[2 * 64 + lane], b11 = Bp[3 * 64 + lane];
    sh8 b20 = Bp[4 * 64 + lane], b21 = Bp[5 * 64 + lane];
    sh8 b30 = Bp[6 * 64 + lane], b31 = Bp[7 * 64 + lane];
    float b2c0 = Wf[WF_B2 + m],      b2c1 = Wf[WF_B2 + 16 + m];
    float b2c2 = Wf[WF_B2 + 32 + m], b2c3 = Wf[WF_B2 + 48 + m];
    float g2c0 = Wf[WF_G2 + m],      g2c1 = Wf[WF_G2 + 16 + m];
    float g2c2 = Wf[WF_G2 + 32 + m], g2c3 = Wf[WF_G2 + 48 + m];
    float e2c0 = Wf[WF_BE2 + m],      e2c1 = Wf[WF_BE2 + 16 + m];
    float e2c2 = Wf[WF_BE2 + 32 + m], e2c3 = Wf[WF_BE2 + 48 + m];
    float w3c0 = Wf[WF_W3 + m],      w3c1 = Wf[WF_W3 + 16 + m];
    float w3c2 = Wf[WF_W3 + 32 + m], w3c3 = Wf[WF_W3 + 48 + m];
    float b3v = Wf[WF_B3];
    const float* G1l = Wf + WF_G1 + quad * 8;
    const float* BE1l = Wf + WF_BE1 + quad * 8;

    const long TILES = B_CNT / 16;                    // 31250
    const long stride = (long)gridDim.x * 4;
    long tile = (long)blockIdx.x * 4 + wv;
    if (tile >= TILES) return;

    int r0 = (int)(tile * 16 + m);
    const float4* Au = (const float4*)(A + (long)userIdx[r0] * 64);
    const float4* As = (const float4*)(A + (long)(servIdx[r0] + U_CNT) * 64);
    float4 bu0 = Au[quad * 2], bu1 = Au[quad * 2 + 1], bu2 = Au[8 + quad * 2], bu3 = Au[9 + quad * 2];
    float4 bs0 = As[quad * 2], bs1 = As[quad * 2 + 1], bs2 = As[8 + quad * 2], bs3 = As[9 + quad * 2];
    long tn = tile + stride;
    int uin = 0, sin = 0;
    if (tn < TILES) {
        int rn = (int)(tn * 16 + m);
        uin = userIdx[rn];
        sin = servIdx[rn] + U_CNT;
    }

    while (true) {
        float zl[8], zh[8];
        zl[0] = bu0.x + bs0.x; zl[1] = bu0.y + bs0.y; zl[2] = bu0.z + bs0.z; zl[3] = bu0.w + bs0.w;
        zl[4] = bu1.x + bs1.x; zl[5] = bu1.y + bs1.y; zl[6] = bu1.z + bs1.z; zl[7] = bu1.w + bs1.w;
        zh[0] = bu2.x + bs2.x; zh[1] = bu2.y + bs2.y; zh[2] = bu2.z + bs2.z; zh[3] = bu2.w + bs2.w;
        zh[4] = bu3.x + bs3.x; zh[5] = bu3.y + bs3.y; zh[6] = bu3.z + bs3.z; zh[7] = bu3.w + bs3.w;

        long tcur = tile;
        bool have_next = (tn < TILES);
        if (have_next) {
            const float4* Au2 = (const float4*)(A + (long)uin * 64);
            const float4* As2 = (const float4*)(A + (long)sin * 64);
            bu0 = Au2[quad * 2]; bu1 = Au2[quad * 2 + 1]; bu2 = Au2[8 + quad * 2]; bu3 = Au2[9 + quad * 2];
            bs0 = As2[quad * 2]; bs1 = As2[quad * 2 + 1]; bs2 = As2[8 + quad * 2]; bs3 = As2[9 + quad * 2];
            long tnn = tn + stride;
            if (tnn < TILES) {
                int rnn = (int)(tnn * 16 + m);
                uin = userIdx[rnn];
                sin = servIdx[rnn] + U_CNT;
            }
            tile = tn;
            tn = tnn;
        }

        float s = 0.f, q = 0.f;
        #pragma unroll
        for (int j = 0; j < 8; ++j) {
            s += zl[j] + zh[j];
            q = fmaf(zl[j], zl[j], q);
            q = fmaf(zh[j], zh[j], q);
        }
        s += __shfl_xor(s, 16, 64); s += __shfl_xor(s, 32, 64);
        q += __shfl_xor(q, 16, 64); q += __shfl_xor(q, 32, 64);
        float mu = s * (1.f / 64.f);
        float rs = rsqrtf(q * (1.f / 64.f) - mu * mu + LN_EPS);
        float nm = -mu * rs;

        sh8 a0, a1;
        #pragma unroll
        for (int j = 0; j < 8; ++j) {
            float h0 = fmaxf(fmaf(fmaf(zl[j], rs, nm), G1l[j],      BE1l[j]),      0.f);
            float h1 = fmaxf(fmaf(fmaf(zh[j], rs, nm), G1l[32 + j], BE1l[32 + j]), 0.f);
            a0[j] = (short)f2bs(h0);
            a1[j] = (short)f2bs(h1);
        }

        f4v acc0 = {0.f, 0.f, 0.f, 0.f}, acc1 = acc0, acc2 = acc0, acc3 = acc0;
        acc0 = __builtin_amdgcn_mfma_f32_16x16x32_bf16(a0, b00, acc0, 0, 0, 0);
        acc0 = __builtin_amdgcn_mfma_f32_16x16x32_bf16(a1, b01, acc0, 0, 0, 0);
        acc1 = __builtin_amdgcn_mfma_f32_16x16x32_bf16(a0, b10, acc1, 0, 0, 0);
        acc1 = __builtin_amdgcn_mfma_f32_16x16x32_bf16(a1, b11, acc1, 0, 0, 0);
        acc2 = __builtin_amdgcn_mfma_f32_16x16x32_bf16(a0, b20, acc2, 0, 0, 0);
        acc2 = __builtin_amdgcn_mfma_f32_16x16x32_bf16(a1, b21, acc2, 0, 0, 0);
        acc3 = __builtin_amdgcn_mfma_f32_16x16x32_bf16(a0, b30, acc3, 0, 0, 0);
        acc3 = __builtin_amdgcn_mfma_f32_16x16x32_bf16(a1, b31, acc3, 0, 0, 0);

        float y0[4], y1[4], y2[4], y3[4];
        float srow[4], qrow[4];
        #pragma unroll
        for (int reg = 0; reg < 4; ++reg) {
            y0[reg] = acc0[reg] + b2c0;
            y1[reg] = acc1[reg] + b2c1;
            y2[reg] = acc2[reg] + b2c2;
            y3[reg] = acc3[reg] + b2c3;
            srow[reg] = (y0[reg] + y1[reg]) + (y2[reg] + y3[reg]);
            float qa = y0[reg] * y0[reg];
            qa = fmaf(y1[reg], y1[reg], qa);
            qa = fmaf(y2[reg], y2[reg], qa);
            qa = fmaf(y3[reg], y3[reg], qa);
            qrow[reg] = qa;
        }
        #pragma unroll
        for (int reg = 0; reg < 4; ++reg) {           // DPP: 16-lane sums, no LDS
            srow[reg] = rowsum16(srow[reg]);
            qrow[reg] = rowsum16(qrow[reg]);
        }
        float o[4];
        #pragma unroll
        for (int reg = 0; reg < 4; ++reg) {
            float mu2 = srow[reg] * (1.f / 64.f);
            float rs2 = rsqrtf(qrow[reg] * (1.f / 64.f) - mu2 * mu2 + LN_EPS);
            float nm2 = -mu2 * rs2;
            float t0 = fmaxf(fmaf(fmaf(y0[reg], rs2, nm2), g2c0, e2c0), 0.f);
            float t1 = fmaxf(fmaf(fmaf(y1[reg], rs2, nm2), g2c1, e2c1), 0.f);
            float t2 = fmaxf(fmaf(fmaf(y2[reg], rs2, nm2), g2c2, e2c2), 0.f);
            float t3 = fmaxf(fmaf(fmaf(y3[reg], rs2, nm2), g2c3, e2c3), 0.f);
            o[reg] = fmaf(t0, w3c0, fmaf(t1, w3c1, fmaf(t2, w3c2, t3 * w3c3)));
        }
        #pragma unroll
        for (int reg = 0; reg < 4; ++reg) o[reg] = rowsum16(o[reg]);
        if (m == 0) {
            long rb = tcur * 16 + quad * 4;
            if (isf32) {
                float4 v = make_float4(o[0] + b3v, o[1] + b3v, o[2] + b3v, o[3] + b3v);
                *(float4*)((float*)out + rb) = v;
            } else {
                ushort4 v;
                v.x = f2bs(o[0] + b3v);
                v.y = f2bs(o[1] + b3v);
                v.z = f2bs(o[2] + b3v);
                v.w = f2bs(o[3] + b3v);
                *(ushort4*)((bf16*)out + rb) = v;
            }
        }
        if (!have_next) break;
    }
}

extern "C" __attribute__((visibility("default")))
void kernel_launch(void* const* d_in, const int* in_sizes, int n_in,
                   void* d_out, int out_size, void* d_ws, size_t ws_size,
                   hipStream_t stream) {
    const void* uE   = d_in[0];
    const void* iE   = d_in[1];
    const void* uHy  = d_in[2];
    const void* iHy  = d_in[3];
    const void* W1   = d_in[4];
    const void* b1   = d_in[5];
    const void* g1   = d_in[6];
    const void* be1  = d_in[7];
    const void* W2   = d_in[8];
    const void* b2   = d_in[9];
    const void* g2   = d_in[10];
    const void* be2  = d_in[11];
    const void* W3   = d_in[12];
    const void* b3   = d_in[13];
    const void* adj_vals = d_in[14];
    const int*  adj_rows = (const int*)d_in[15];
    const int*  adj_cols = (const int*)d_in[16];
    const int*  userIdx  = (const int*)d_in[17];
    const int*  servIdx  = (const int*)d_in[18];

    char* w = (char*)d_ws;
    size_t off = 0;
    auto alloc = [&](size_t bytes) -> char* {
        char* p = w + off;
        off += (bytes + 255) & ~(size_t)255;
        return p;
    };
    unsigned short* EtHi = (unsigned short*)alloc((size_t)ET_U16 * 2);
    unsigned short* EtLo = (unsigned short*)alloc((size_t)ET_U16 * 2);
    unsigned short* GuHi = (unsigned short*)alloc((size_t)GU_U16 * 2);
    unsigned short* GuLo = (unsigned short*)alloc((size_t)GU_U16 * 2);
    unsigned short* VHi  = (unsigned short*)alloc((size_t)V_U16 * 2);
    unsigned short* VLo  = (unsigned short*)alloc((size_t)V_U16 * 2);
    unsigned short* wTH  = (unsigned short*)alloc((size_t)WT_U16 * 2);
    unsigned short* wTL  = (unsigned short*)alloc((size_t)WT_U16 * 2);
    float* yT   = (float*)alloc((size_t)D_DIM * UPAD * 4);
    float* uEt  = (float*)alloc((size_t)D_DIM * UPAD * 4);
    float* Pc   = (float*)alloc((size_t)2 * D_DIM * H_DIM * 4);
    float* A    = (float*)alloc((size_t)N_CNT * H_DIM * 4);
    float* Wf   = (float*)alloc((size_t)WF_TOT * 4);
    unsigned short* Wb = (unsigned short*)alloc((size_t)4096 * 2);
    // zero-init span: PkS+PkU contiguous (edge-pack pads must be 0 each run)
    unsigned short* PkS = (unsigned short*)alloc((size_t)PKS_U16 * 2);
    unsigned short* PkU = (unsigned short*)alloc((size_t)PKU_U16 * 2);
    size_t zspan = (size_t)((char*)(PkU + PKU_U16) - (char*)PkS);

    hipMemsetAsync(PkS, 0, zspan, stream);
    k_pre<<<PRE_UNITS, 256, 0, stream>>>(iE, EtHi, EtLo, adj_rows, adj_cols,
                                         adj_vals, PkS, PkU, uEt,
                                         uHy, iHy, W1, W2, b1, g1, be1,
                                         b2, g2, be2, W3, b3, Pc, Wf, Wb, uE);
    k_heavy<<<HV_BLOCKS, 512, 0, stream>>>(EtHi, EtLo, PkU, GuHi, GuLo, yT);
    k_midA<<<176, 256, 0, stream>>>(yT, uEt, Pc, VHi, VLo);
    k_midB<<<44, 256, 0, stream>>>(GuHi, GuLo, VHi, VLo, Wf, A, wTH, wTL);
    k_as<<<183, 256, 0, stream>>>(wTH, wTL, PkS, A);
    HyperModel_65755949301857_kernel<<<MLP_BLOCKS, 256, 0, stream>>>(
        A, userIdx, servIdx, Wf, Wb, d_out, uE);
}